// Round 1
// baseline (192.755 us; speedup 1.0000x reference)
//
#include <hip/hip_runtime.h>

#define D 32
#define EPS 1e-5f

// Pass A: per-edge msg = relu(h[src] @ W[etype]); accumulate per-dim sum/sumsq
// for BatchNorm batch stats, and per-dst edge counts.
// Mapping: 32 lanes per edge (one lane per output dim o), 8 edges per 256-block.
__global__ void edge_stats_kernel(const float* __restrict__ h,
                                  const float* __restrict__ W,
                                  const int* __restrict__ src,
                                  const int* __restrict__ dst,
                                  const int* __restrict__ etype,
                                  float* __restrict__ stat_sum,   // [D]
                                  float* __restrict__ stat_sq,    // [D]
                                  float* __restrict__ cnt,        // [N]
                                  int E)
{
    const int o    = threadIdx.x & 31;
    const int slot = threadIdx.x >> 5;          // 0..7
    __shared__ float s_sum[D];
    __shared__ float s_sq[D];
    if (threadIdx.x < D) { s_sum[threadIdx.x] = 0.f; s_sq[threadIdx.x] = 0.f; }
    __syncthreads();

    float lsum = 0.f, lsq = 0.f;
    const int stride = gridDim.x * 8;
    for (int e = blockIdx.x * 8 + slot; e < E; e += stride) {
        const int s = src[e];
        const int r = etype[e];
        const float hv = h[s * D + o];          // lane o holds h_row[o]
        const float* w = W + r * (D * D) + o;   // column o of relation matrix
        float acc = 0.f;
#pragma unroll
        for (int d = 0; d < D; ++d) {
            // broadcast h_row[d] from lane d of this 32-lane group
            acc = fmaf(__shfl(hv, d, 32), w[d * D], acc);
        }
        acc = fmaxf(acc, 0.f);                  // ReLU
        lsum += acc;
        lsq  += acc * acc;
        if (o == 0) atomicAdd(&cnt[dst[e]], 1.0f);
    }
    atomicAdd(&s_sum[o], lsum);
    atomicAdd(&s_sq[o], lsq);
    __syncthreads();
    if (threadIdx.x < D) {
        atomicAdd(&stat_sum[threadIdx.x], s_sum[threadIdx.x]);
        atomicAdd(&stat_sq[threadIdx.x],  s_sq[threadIdx.x]);
    }
}

// Pass B: fold BN stats + gamma/beta into per-dim scale/shift.
__global__ void bn_fold_kernel(const float* __restrict__ stat_sum,
                               const float* __restrict__ stat_sq,
                               const float* __restrict__ gamma,
                               const float* __restrict__ beta,
                               float* __restrict__ scale,
                               float* __restrict__ shift,
                               float invE)
{
    const int o = threadIdx.x;
    const float mu  = stat_sum[o] * invE;
    const float var = fmaxf(stat_sq[o] * invE - mu * mu, 0.f);  // biased var
    const float is  = rsqrtf(var + EPS);
    const float sc  = gamma[o] * is;
    scale[o] = sc;
    shift[o] = fmaf(-mu, sc, beta[o]);
}

// Pass C: recompute msg, apply BN affine, scatter-add into out[dst].
__global__ void edge_scatter_kernel(const float* __restrict__ h,
                                    const float* __restrict__ W,
                                    const int* __restrict__ src,
                                    const int* __restrict__ dst,
                                    const int* __restrict__ etype,
                                    const float* __restrict__ scale,
                                    const float* __restrict__ shift,
                                    float* __restrict__ out,
                                    int E)
{
    const int o    = threadIdx.x & 31;
    const int slot = threadIdx.x >> 5;
    const float sc = scale[o];
    const float sh = shift[o];
    const int stride = gridDim.x * 8;
    for (int e = blockIdx.x * 8 + slot; e < E; e += stride) {
        const int s = src[e];
        const int r = etype[e];
        const float hv = h[s * D + o];
        const float* w = W + r * (D * D) + o;
        float acc = 0.f;
#pragma unroll
        for (int d = 0; d < D; ++d) {
            acc = fmaf(__shfl(hv, d, 32), w[d * D], acc);
        }
        acc = fmaxf(acc, 0.f);
        atomicAdd(&out[dst[e] * D + o], fmaf(acc, sc, sh));
    }
}

// Pass D: divide node sums by max(count, 1).
__global__ void finalize_kernel(float* __restrict__ out,
                                const float* __restrict__ cnt,
                                int total)
{
    const int i = blockIdx.x * blockDim.x + threadIdx.x;
    if (i < total) out[i] = out[i] / fmaxf(cnt[i >> 5], 1.0f);
}

extern "C" void kernel_launch(void* const* d_in, const int* in_sizes, int n_in,
                              void* d_out, int out_size, void* d_ws, size_t ws_size,
                              hipStream_t stream)
{
    const float* h     = (const float*)d_in[0];   // [N, D]
    const float* W     = (const float*)d_in[1];   // [R, D, D]
    const float* gamma = (const float*)d_in[2];   // [D]
    const float* beta  = (const float*)d_in[3];   // [D]
    const int*   src   = (const int*)d_in[4];     // [E]
    const int*   dst   = (const int*)d_in[5];     // [E]
    const int*   etype = (const int*)d_in[6];     // [E]
    float* out = (float*)d_out;                   // [N, D]

    const int E = in_sizes[4];
    const int N = in_sizes[0] / D;

    // Workspace layout (floats): sum[D] | sumsq[D] | scale[D] | shift[D] | cnt[N]
    float* stat_sum = (float*)d_ws;
    float* stat_sq  = stat_sum + D;
    float* scale    = stat_sq + D;
    float* shift    = scale + D;
    float* cnt      = shift + D;

    hipMemsetAsync(d_ws, 0, (size_t)(4 * D + N) * sizeof(float), stream);
    hipMemsetAsync(d_out, 0, (size_t)out_size * sizeof(float), stream);

    const int blocks = 2048;   // grid-stride: ~12 edges per slot-thread
    edge_stats_kernel<<<blocks, 256, 0, stream>>>(h, W, src, dst, etype,
                                                  stat_sum, stat_sq, cnt, E);
    bn_fold_kernel<<<1, D, 0, stream>>>(stat_sum, stat_sq, gamma, beta,
                                        scale, shift, 1.0f / (float)E);
    edge_scatter_kernel<<<blocks, 256, 0, stream>>>(h, W, src, dst, etype,
                                                    scale, shift, out, E);
    const int total = N * D;
    finalize_kernel<<<(total + 255) / 256, 256, 0, stream>>>(out, cnt, total);
}